// Round 1
// baseline (535.866 us; speedup 1.0000x reference)
//
#include <hip/hip_runtime.h>

#define NN 50000
#define FD 128
#define NE 800000
#define NG 512
#define NC 16
#define NL 3
#define NTOT 100000
#define NBLK 391            // ceil(100000/256) and ceil(50000/128)
#define NBUCK 196           // ceil(100000/512) slot-buckets
#define CAP 10240           // per-bucket capacity (avg 8163, sigma ~90)
#define BINTILE 2048
#define NBINBLK 782         // ceil(1600000/2048)
#define BNEPS 1e-5f
#define LOGITS_N (NL*NG*NC)

typedef unsigned short u16;
typedef unsigned char u8;
typedef __attribute__((ext_vector_type(8))) short short8;
typedef __attribute__((ext_vector_type(4))) float f32x4;

// ---- workspace layout (bytes), offsets 512-aligned ----
#define OFF_GCNT     0ul          // 2*512 int
#define OFF_BCUR     4096ul       // 196 int (per-bucket fill count)
#define OFF_ACC      5120ul       // 512 f32 (BN stat accumulators: S[256],Q[256])
#define MEMSET_BYTES 7168ul       // covers GCNT + BCUR + ACC
#define OFF_USTART   7680ul       // 513 int
#define OFF_ISTART   10240ul      // 513 int
#define OFF_INVCNT   12800ul      // 512 f32
#define OFF_BNSC     14848ul      // 256 f32
#define OFF_BNSH     15872ul      // 256 f32
#define OFF_ROWRANGE 16896ul      // 100000 int2
#define OFF_WB       817152ul     // 6*128*256 bf16 (only layer-0 block used now)
#define OFF_CSR      1210368ul    // 196*10240 int (binned, then CSR in place)
#define OFF_N0I      9238528ul    // 50000*128 bf16 (ping-pong pair 0, item)
#define OFF_N0U      22038528ul   // 50000*128 bf16 (ping-pong pair 0, user)
#define OFF_N1U      34838528ul   // 50000*128 bf16 (ping-pong pair 1, user)
#define OFF_N1I      47638528ul   // 50000*128 bf16 (ping-pong pair 1, item)
#define OFF_XU0      60438528ul   // 50000*128 bf16 (initial cast)
#define OFF_XI0      73238528ul   // 50000*128 bf16 (initial cast)
// WBs/bvec overlap the head of xi0: xi0 is only read by layer-0 gather/gemm,
// both of which complete before the first k_bnfold writes here.
#define OFF_WBS      73238528ul   // 2*128*256 bf16 scaled weights (current layer)
#define OFF_BVEC     73369600ul   // b1[2][128] | b2[2][128] f32 fold vectors

static __device__ __forceinline__ float bf2f(u16 v) {
  return __uint_as_float(((unsigned)v) << 16);
}
static __device__ __forceinline__ u16 f2bf(float f) {
  unsigned u = __float_as_uint(f);
  return (u16)((u + 0x7FFFu + ((u >> 16) & 1u)) >> 16);
}
// accumulate 8 packed bf16 (int4) into float[8]; RELU=1 applies max(0,.) per elem
template<int RELU>
static __device__ __forceinline__ void accT8(float* a, int4 v) {
  unsigned w[4] = {(unsigned)v.x, (unsigned)v.y, (unsigned)v.z, (unsigned)v.w};
  #pragma unroll
  for (int i = 0; i < 4; i++) {
    float lo = __uint_as_float(w[i] << 16);
    float hi = __uint_as_float(w[i] & 0xffff0000u);
    if (RELU) { lo = lo > 0.f ? lo : 0.f; hi = hi > 0.f ? hi : 0.f; }
    a[2*i]   += lo;
    a[2*i+1] += hi;
  }
}
// unpack 8 bf16 (int4) into float[8]
static __device__ __forceinline__ void unp8(float* a, int4 v) {
  a[0] = __uint_as_float(((unsigned)v.x) << 16);
  a[1] = __uint_as_float(((unsigned)v.x) & 0xffff0000u);
  a[2] = __uint_as_float(((unsigned)v.y) << 16);
  a[3] = __uint_as_float(((unsigned)v.y) & 0xffff0000u);
  a[4] = __uint_as_float(((unsigned)v.z) << 16);
  a[5] = __uint_as_float(((unsigned)v.z) & 0xffff0000u);
  a[6] = __uint_as_float(((unsigned)v.w) << 16);
  a[7] = __uint_as_float(((unsigned)v.w) & 0xffff0000u);
}
// relu on 2 packed bf16 without unpacking (zero any half with sign bit set)
static __device__ __forceinline__ int relu2(int w) {
  int lo = (w & 0x00008000) ? 0 : (w & 0x0000FFFF);
  int hi = (w < 0)          ? 0 : (int)(w & 0xFFFF0000u);
  return lo | hi;
}

__global__ __launch_bounds__(256) void k_hist_batch(const int* __restrict__ bu,
                                                    const int* __restrict__ bi,
                                                    int* __restrict__ gcnt) {
  int i = blockIdx.x*256 + threadIdx.x;
  if (i >= NTOT) return;
  int type = i >= NN;
  int g = type ? bi[i-NN] : bu[i];
  atomicAdd(&gcnt[type*NG + g], 1);
}

// scan per-type graph counts -> contiguous row ranges (batch ids are sorted)
__global__ __launch_bounds__(512) void k_scan_g(const int* __restrict__ gcnt,
                                                int* __restrict__ ustart,
                                                int* __restrict__ istart,
                                                float* __restrict__ invcnt) {
  __shared__ int pu[512], pi[512];
  int t = threadIdx.x;
  int cu = gcnt[t], ci = gcnt[NG + t];
  pu[t] = cu; pi[t] = ci;
  __syncthreads();
  for (int off = 1; off < 512; off <<= 1) {
    int vu = (t >= off) ? pu[t-off] : 0;
    int vi = (t >= off) ? pi[t-off] : 0;
    __syncthreads();
    pu[t] += vu; pi[t] += vi;
    __syncthreads();
  }
  ustart[t] = pu[t] - cu;
  istart[t] = pi[t] - ci;
  if (t == 511) { ustart[NG] = pu[511]; istart[NG] = pi[511]; }
  int c = cu + ci;
  invcnt[t] = 1.0f / (float)(c > 0 ? c : 1);
}

// bucket edges by dst-slot>>9 into fixed-capacity regions. Entry packed to 4B:
// (lslot:9 | src:17). Coalesced run writes via LDS reorder. 2048-edge tiles.
__global__ __launch_bounds__(256) void k_bin(const int* __restrict__ eu2i,
                                             const int* __restrict__ ei2u,
                                             int* __restrict__ bcursor,
                                             int* __restrict__ binned) {
  __shared__ int hist[256];
  __shared__ int scan[256];
  __shared__ int gbase[256];
  __shared__ int rbuf[BINTILE];
  __shared__ u8 rbk[BINTILE];
  int tid = threadIdx.x;
  int base = blockIdx.x * BINTILE;
  hist[tid] = 0;
  __syncthreads();
  int packr[8], bkr[8], rankr[8];
  #pragma unroll
  for (int c = 0; c < 8; c++) {
    int idx = base + c*256 + tid;
    if (idx < 2*NE) {
      int rel = idx >= NE;
      int e = rel ? idx - NE : idx;
      const int* edge = rel ? ei2u : eu2i;
      int s = edge[e];
      int d = edge[NE + e];
      int slot = d + (rel ? NN : 0);
      int bk = slot >> 9;
      bkr[c] = bk;
      packr[c] = ((slot & 511) << 17) | s;
      rankr[c] = atomicAdd(&hist[bk], 1);
    } else bkr[c] = -1;
  }
  __syncthreads();
  scan[tid] = hist[tid];
  __syncthreads();
  for (int o = 1; o < 256; o <<= 1) {
    int v = (tid >= o) ? scan[tid - o] : 0;
    __syncthreads();
    scan[tid] += v;
    __syncthreads();
  }
  if (tid < NBUCK && hist[tid] > 0)
    gbase[tid] = atomicAdd(&bcursor[tid], hist[tid]);
  __syncthreads();
  #pragma unroll
  for (int c = 0; c < 8; c++) {
    if (bkr[c] >= 0) {
      int bk = bkr[c];
      int lpos = scan[bk] - hist[bk] + rankr[c];
      rbuf[lpos] = packr[c];
      rbk[lpos] = (u8)bk;
    }
  }
  __syncthreads();
  int nv = min(BINTILE, 2*NE - base);
  for (int j = tid; j < nv; j += 256) {
    int bk = rbk[j];
    int outpos = bk*CAP + gbase[bk] + (j - (scan[bk] - hist[bk]));
    binned[outpos] = rbuf[j];
  }
}

// one block per bucket: local hist+scan -> rowrange, LDS-staged scatter,
// CSR written IN PLACE over the binned region (block-private).
__global__ __launch_bounds__(256) void k_csrbuild(const int* __restrict__ bcursor,
                                                  int* __restrict__ csrbin,
                                                  int2* __restrict__ rowrange) {
  __shared__ int lcnt[512];
  __shared__ int scan2[256];
  __shared__ int lcsr[CAP];
  int b = blockIdx.x;
  int tid = threadIdx.x;
  int slot0 = b << 9;
  int nslots = min(512, NTOT - slot0);
  int n = bcursor[b];
  int gb = b * CAP;
  lcnt[tid] = 0; lcnt[tid + 256] = 0;
  __syncthreads();
  for (int i = tid; i < n; i += 256) {
    int e = csrbin[gb + i];
    atomicAdd(&lcnt[e >> 17], 1);
  }
  __syncthreads();
  int v0 = lcnt[2*tid], v1 = lcnt[2*tid + 1];
  int ps = v0 + v1;
  scan2[tid] = ps;
  __syncthreads();
  for (int o = 1; o < 256; o <<= 1) {
    int v = (tid >= o) ? scan2[tid - o] : 0;
    __syncthreads();
    scan2[tid] += v;
    __syncthreads();
  }
  int e0 = scan2[tid] - ps;       // exclusive prefix for slot 2*tid
  int e1 = e0 + v0;
  if (2*tid < nslots)     rowrange[slot0 + 2*tid]     = make_int2(gb + e0, gb + e0 + v0);
  if (2*tid + 1 < nslots) rowrange[slot0 + 2*tid + 1] = make_int2(gb + e1, gb + e1 + v1);
  __syncthreads();
  lcnt[2*tid] = e0; lcnt[2*tid + 1] = e1;   // cursors
  __syncthreads();
  for (int i = tid; i < n; i += 256) {
    int e = csrbin[gb + i];
    int pos = atomicAdd(&lcnt[e >> 17], 1);
    lcsr[pos] = e & 0x1FFFF;
  }
  __syncthreads();
  for (int i = tid; i < n; i += 256) csrbin[gb + i] = lcsr[i];
}

// fp32 -> bf16 cast of initial features
__global__ __launch_bounds__(256) void k_castX(const float* __restrict__ xu,
                                               const float* __restrict__ xi,
                                               u16* __restrict__ xbu,
                                               u16* __restrict__ xbi) {
  int b = blockIdx.x;
  int half = b >= 6250;
  const float* src = half ? xi : xu;
  u16* dst = half ? xbi : xbu;
  int i = ((half ? b - 6250 : b)*256 + threadIdx.x) * 4;
  float4 v = *(const float4*)(src + i);
  ushort4 o = { f2bf(v.x), f2bf(v.y), f2bf(v.z), f2bf(v.w) };
  *(ushort4*)(dst + i) = o;
}

// WB[lr][h][k]: k<128 -> Wrel[l][h][k], else Wroot[l][h][k-128]   (bf16)
// launched with 256 blocks now: only layer-0 (lr 0,1) weights needed unscaled.
__global__ __launch_bounds__(256) void k_castW(const float* __restrict__ WrelA,
                                               const float* __restrict__ WrootA,
                                               const float* __restrict__ WrelB,
                                               const float* __restrict__ WrootB,
                                               u16* __restrict__ WB) {
  int idx = blockIdx.x*256 + threadIdx.x;
  int lr = idx >> 15;
  int rem = idx & 32767;
  int h = rem >> 8;
  int k = rem & 255;
  int l = lr >> 1;
  int rel = lr & 1;
  const float* Wr = rel ? WrelB : WrelA;
  const float* Wo = rel ? WrootB : WrootA;
  float v = (k < FD) ? Wr[(l*FD + h)*FD + k] : Wo[(l*FD + h)*FD + (k-FD)];
  WB[idx] = f2bf(v);
}

// per-layer BN fold for layer l (l = 1 or 2):
//   WBs[rel][h][k] = (k<128 ? Wrel[l][h][k]*sc_src[k] : Wroot[l][h][k-128]*sc_dst[k-128])
//   bvec[0..255]   = b1[rel][h] = sum_k Wrel[l][h][k]*sh_src[k]   (deg-scaled bias)
//   bvec[256..511] = b2[rel][h] = sum_k Wroot[l][h][k]*sh_dst[k]  (constant bias)
// rel 0 = u2i (src user, dst item), rel 1 = i2u (src item, dst user)
__global__ __launch_bounds__(256) void k_bnfold(const float* __restrict__ WrelA,
                                                const float* __restrict__ WrootA,
                                                const float* __restrict__ WrelB,
                                                const float* __restrict__ WrootB,
                                                int l,
                                                const float* __restrict__ bnsc,
                                                const float* __restrict__ bnsh,
                                                u16* __restrict__ WBs,
                                                float* __restrict__ bvec) {
  int b = blockIdx.x, tid = threadIdx.x;
  if (b < 64) {
    int e = b*256 + tid;          // 16384 entries x 4 consecutive k
    int rel = e >> 13;
    int rem = e & 8191;
    int h = rem >> 6;
    int k0 = (rem & 63) * 4;
    const float* Wr = rel ? WrelB : WrelA;
    const float* Wo = rel ? WrootB : WrootA;
    const float* scs = bnsc + (rel ? 128 : 0);
    const float* scd = bnsc + (rel ? 0 : 128);
    u16 t[4];
    #pragma unroll
    for (int j = 0; j < 4; j++) {
      int k = k0 + j;
      float v = (k < FD) ? Wr[((size_t)l*FD + h)*FD + k] * scs[k]
                         : Wo[((size_t)l*FD + h)*FD + (k - FD)] * scd[k - FD];
      t[j] = f2bf(v);
    }
    ushort4 o = { t[0], t[1], t[2], t[3] };
    *(ushort4*)(WBs + rel*32768 + h*256 + k0) = o;
  } else {
    int vid = (b - 64)*256 + tid; // 0..511
    int kind = vid >> 8;          // 0 = b1 (Wrel, sh_src), 1 = b2 (Wroot, sh_dst)
    int rel = (vid >> 7) & 1;
    int h = vid & 127;
    const float* W = kind ? (rel ? WrootB : WrootA) : (rel ? WrelB : WrelA);
    const float* sh = bnsh + ((kind ^ rel) ? 128 : 0);
    const float* wrow = W + ((size_t)l*FD + h)*FD;
    float s = 0.f;
    #pragma unroll
    for (int k = 0; k < FD; k += 4) {
      float4 wv = *(const float4*)(wrow + k);
      float4 sv = *(const float4*)(sh + k);
      s += wv.x*sv.x + wv.y*sv.y + wv.z*sv.z + wv.w*sv.w;
    }
    bvec[kind*256 + rel*128 + h] = s;
  }
}

// one wave per dst row; 16B/lane loads (16 lanes = one 256B row), quarter-waves
// take different edges; 2 chains x 8-edge iters with index prefetch.
// RELU=1 (layers >0): sources are raw pre-BN activations; relu applied
// in-register, BN affine folded downstream into GEMM weights/bias.
// blocks [0,12500): u2i (curU -> aggI), [12500,25000): i2u (curI -> aggU)
template<int RELU>
__global__ __launch_bounds__(256) void k_gather(const u16* __restrict__ curU,
                                                const u16* __restrict__ curI,
                                                const int2* __restrict__ rowrange,
                                                const int* __restrict__ csr,
                                                u16* __restrict__ aggI,
                                                u16* __restrict__ aggU) {
  int b = blockIdx.x;
  int half = b >= 12500;
  int blk = half ? b - 12500 : b;
  const u16* src = half ? curI : curU;
  u16* out = half ? aggU : aggI;
  int slotbase = half ? NN : 0;
  int wid = __builtin_amdgcn_readfirstlane(threadIdx.x >> 6);
  int row = blk*4 + wid;
  int lane = threadIdx.x & 63;
  int q = lane >> 4;
  int c16 = (lane & 15) * 8;      // 8 bf16 = 16B per lane
  const u16* sp = src + c16;
  int2 pr = rowrange[slotbase + row];
  int p = pr.x, pe = pr.y;
  float a0[8], a1[8];
  #pragma unroll
  for (int j = 0; j < 8; j++) { a0[j] = 0.f; a1[j] = 0.f; }
  if (p + 8 <= pe) {
    int i0 = csr[p + q], i1 = csr[p + 4 + q];
    while (p + 16 <= pe) {
      int n0 = csr[p + 8 + q], n1 = csr[p + 12 + q];
      int4 v0 = *(const int4*)(sp + (size_t)i0*FD);
      int4 v1 = *(const int4*)(sp + (size_t)i1*FD);
      accT8<RELU>(a0, v0); accT8<RELU>(a1, v1);
      i0 = n0; i1 = n1; p += 8;
    }
    int4 v0 = *(const int4*)(sp + (size_t)i0*FD);
    int4 v1 = *(const int4*)(sp + (size_t)i1*FD);
    accT8<RELU>(a0, v0); accT8<RELU>(a1, v1);
    p += 8;
  }
  int rem = pe - p;               // 0..7
  if (q < rem) {
    int s = csr[p + q];
    accT8<RELU>(a0, *(const int4*)(sp + (size_t)s*FD));
  }
  if (q + 4 < rem) {
    int s = csr[p + 4 + q];
    accT8<RELU>(a1, *(const int4*)(sp + (size_t)s*FD));
  }
  #pragma unroll
  for (int j = 0; j < 8; j++) a0[j] += a1[j];
  #pragma unroll
  for (int j = 0; j < 8; j++) {
    a0[j] += __shfl_xor(a0[j], 16);
    a0[j] += __shfl_xor(a0[j], 32);
  }
  if (q == 0) {
    int4 o;
    o.x = (unsigned)f2bf(a0[0]) | ((unsigned)f2bf(a0[1]) << 16);
    o.y = (unsigned)f2bf(a0[2]) | ((unsigned)f2bf(a0[3]) << 16);
    o.z = (unsigned)f2bf(a0[4]) | ((unsigned)f2bf(a0[5]) << 16);
    o.w = (unsigned)f2bf(a0[6]) | ((unsigned)f2bf(a0[7]) << 16);
    *(int4*)(out + (size_t)row*FD + c16) = o;
  }
}

// MFMA bf16 GEMM: new[n,h] = [agg|cur][n,0:256] @ WB[h,0:256]^T + bias'[n,h]
// 128x128 tile, BK=64, LDS row stride 72 bf16. BN relu-stats -> global atomics.
// fold=1 (layers >0): weights are pre-scaled (WBs), cur rows get relu on
// staging, bias' = bias + b2 + deg(row)*b1  (BN affine of the PREVIOUS layer
// folded in; deg from rowrange).
__global__ __launch_bounds__(256) void k_gemm(u16* __restrict__ newU,
                                              u16* __restrict__ newI,
                                              const u16* __restrict__ curU,
                                              const u16* __restrict__ curI,
                                              const u16* __restrict__ WBl,
                                              const float* __restrict__ bI2U,
                                              const float* __restrict__ bU2I,
                                              float* __restrict__ accSQ,
                                              const float* __restrict__ bvec,
                                              const int2* __restrict__ rowrange,
                                              int fold) {
  __shared__ u16 As[128*72];
  __shared__ u16 Bs[128*72];
  __shared__ float Sred[2][4][128];
  int ty = blockIdx.y;
  u16* A1 = ty ? newI : newU;
  const u16* A2 = ty ? curI : curU;
  const u16* WBp = ty ? WBl : (WBl + 32768);
  const float* bias = ty ? bU2I : bI2U;
  const float* b1p = bvec + (ty ? 0 : 128);
  const float* b2p = bvec + 256 + (ty ? 0 : 128);
  int slot0 = ty ? 0 : NN;        // dst slots: items [0,NN), users [NN,2NN)
  int tid = threadIdx.x;
  int n0 = blockIdx.x * 128;
  int w = __builtin_amdgcn_readfirstlane(tid >> 6);
  int lane = tid & 63;
  int l15 = lane & 15;
  int quad = lane >> 4;
  f32x4 acc[2][8];
  #pragma unroll
  for (int tr = 0; tr < 2; tr++)
    #pragma unroll
    for (int tc = 0; tc < 8; tc++)
      acc[tr][tc] = (f32x4){0.f,0.f,0.f,0.f};

  for (int ch = 0; ch < 4; ch++) {
    const u16* Ap = (ch < 2) ? ((const u16*)A1 + ch*64) : (A2 + (ch-2)*64);
    int dorelu = fold && (ch >= 2);
    #pragma unroll
    for (int i = 0; i < 4; i++) {
      int e = i*256 + tid;
      int r = e >> 3, seg = e & 7;
      int4 v = {0,0,0,0};
      int gr = n0 + r;
      if (gr < NN) v = *(const int4*)(Ap + (size_t)gr*FD + seg*8);
      if (dorelu) { v.x = relu2(v.x); v.y = relu2(v.y); v.z = relu2(v.z); v.w = relu2(v.w); }
      *(int4*)&As[r*72 + seg*8] = v;
    }
    #pragma unroll
    for (int i = 0; i < 4; i++) {
      int e = i*256 + tid;
      int r = e >> 3, seg = e & 7;
      int4 v = *(const int4*)(WBp + r*256 + ch*64 + seg*8);
      *(int4*)&Bs[r*72 + seg*8] = v;
    }
    __syncthreads();
    #pragma unroll
    for (int ks = 0; ks < 2; ks++) {
      int kb = ks*32 + quad*8;
      short8 af0 = *(const short8*)&As[(w*32 + l15)*72 + kb];
      short8 af1 = *(const short8*)&As[(w*32 + 16 + l15)*72 + kb];
      short8 bf[8];
      #pragma unroll
      for (int tc = 0; tc < 8; tc++)
        bf[tc] = *(const short8*)&Bs[(tc*16 + l15)*72 + kb];
      #pragma unroll
      for (int tc = 0; tc < 8; tc++) {
        acc[0][tc] = __builtin_amdgcn_mfma_f32_16x16x32_bf16(af0, bf[tc], acc[0][tc], 0, 0, 0);
        acc[1][tc] = __builtin_amdgcn_mfma_f32_16x16x32_bf16(af1, bf[tc], acc[1][tc], 0, 0, 0);
      }
    }
    __syncthreads();
  }
  float sv[8], qv[8], bj[8], b1j[8];
  #pragma unroll
  for (int tc = 0; tc < 8; tc++) {
    int col = tc*16 + l15;
    float base = bias[col];
    if (fold) { base += b2p[col]; b1j[tc] = b1p[col]; } else b1j[tc] = 0.f;
    bj[tc] = base;
    sv[tc] = 0.f; qv[tc] = 0.f;
  }
  float dg[2][4] = {{0.f,0.f,0.f,0.f},{0.f,0.f,0.f,0.f}};
  if (fold) {
    #pragma unroll
    for (int tr = 0; tr < 2; tr++)
      #pragma unroll
      for (int gq = 0; gq < 4; gq++) {
        int r = n0 + w*32 + tr*16 + quad*4 + gq;
        if (r < NN) {
          int2 rr = rowrange[slot0 + r];
          dg[tr][gq] = (float)(rr.y - rr.x);
        }
      }
  }
  #pragma unroll
  for (int tr = 0; tr < 2; tr++) {
    int rbase = n0 + w*32 + tr*16 + quad*4;
    #pragma unroll
    for (int tc = 0; tc < 8; tc++) {
      int col = tc*16 + l15;
      #pragma unroll
      for (int g = 0; g < 4; g++) {
        int r = rbase + g;
        if (r < NN) {
          float v = acc[tr][tc][g] + bj[tc] + dg[tr][g]*b1j[tc];
          float y = v > 0.f ? v : 0.f;
          sv[tc] += y; qv[tc] += y*y;
          A1[(size_t)r*FD + col] = f2bf(v);
        }
      }
    }
  }
  #pragma unroll
  for (int tc = 0; tc < 8; tc++) {
    sv[tc] += __shfl_xor(sv[tc], 16); qv[tc] += __shfl_xor(qv[tc], 16);
    sv[tc] += __shfl_xor(sv[tc], 32); qv[tc] += __shfl_xor(qv[tc], 32);
  }
  if (quad == 0) {
    #pragma unroll
    for (int tc = 0; tc < 8; tc++) {
      Sred[0][w][tc*16 + l15] = sv[tc];
      Sred[1][w][tc*16 + l15] = qv[tc];
    }
  }
  __syncthreads();
  if (tid < 128) {
    float s = Sred[0][0][tid] + Sred[0][1][tid] + Sred[0][2][tid] + Sred[0][3][tid];
    float q = Sred[1][0][tid] + Sred[1][1][tid] + Sred[1][2][tid] + Sred[1][3][tid];
    atomicAdd(&accSQ[ty*128 + tid], s);
    atomicAdd(&accSQ[256 + ty*128 + tid], q);
  }
}

// tiny: fold accumulated stats -> scale/shift; re-zero accumulators for next layer
__global__ __launch_bounds__(256) void k_bnfinal(float* __restrict__ accSQ,
                                                 const float* __restrict__ gu,
                                                 const float* __restrict__ bu,
                                                 const float* __restrict__ gi,
                                                 const float* __restrict__ bi,
                                                 float* __restrict__ bnsc,
                                                 float* __restrict__ bnsh) {
  int tid = threadIdx.x;
  int type = tid >> 7;            // 0=user, 1=item
  int c = tid & 127;
  float s = accSQ[tid];
  float q = accSQ[256 + tid];
  accSQ[tid] = 0.f;
  accSQ[256 + tid] = 0.f;
  float inv = 1.0f / (float)NN;
  float mean = s * inv;
  float var = q * inv - mean*mean;
  float rstd = rsqrtf(var + BNEPS);
  float g = type ? gi[c] : gu[c];
  float bb = type ? bi[c] : bu[c];
  float sc = rstd * g;
  bnsc[tid] = sc;
  bnsh[tid] = bb - mean * sc;
}

// mean-pool over raw pre-BN activations, one block per graph; BN affine
// reconstructed per type:  sc*sum(relu) + n_type*sh.  Read-only on node data.
__global__ __launch_bounds__(256) void k_pool(const u16* __restrict__ newU,
                                              const u16* __restrict__ newI,
                                              const int* __restrict__ ustart,
                                              const int* __restrict__ istart,
                                              const float* __restrict__ bnsc,
                                              const float* __restrict__ bnsh,
                                              const float* __restrict__ invcnt,
                                              float* __restrict__ feats) {
  __shared__ float red[16][128];
  int tid = threadIdx.x;
  int g = blockIdx.x;
  int rt = tid >> 4;        // 0..15 row thread
  int c8 = (tid & 15) * 8;  // col group base
  float tot[8];
  #pragma unroll
  for (int j = 0; j < 8; j++) tot[j] = 0.f;
  #pragma unroll
  for (int type = 0; type < 2; type++) {
    const u16* in = type ? newI : newU;
    const int* st = type ? istart : ustart;
    int rs = st[g], re = st[g+1];
    float acc[8];
    #pragma unroll
    for (int j = 0; j < 8; j++) acc[j] = 0.f;
    int r = rs + rt;
    for (; r + 16 < re; r += 32) {
      int4 v0 = *(const int4*)(in + (size_t)r*FD + c8);
      int4 v1 = *(const int4*)(in + (size_t)(r+16)*FD + c8);
      float f0[8], f1[8];
      unp8(f0, v0); unp8(f1, v1);
      #pragma unroll
      for (int j = 0; j < 8; j++)
        acc[j] += (f0[j] > 0.f ? f0[j] : 0.f) + (f1[j] > 0.f ? f1[j] : 0.f);
    }
    for (; r < re; r += 16) {
      int4 v0 = *(const int4*)(in + (size_t)r*FD + c8);
      float f0[8];
      unp8(f0, v0);
      #pragma unroll
      for (int j = 0; j < 8; j++) acc[j] += f0[j] > 0.f ? f0[j] : 0.f;
    }
    #pragma unroll
    for (int j = 0; j < 8; j++) tot[j] += acc[j] * bnsc[type*128 + c8 + j];
    if (rt == 0) {
      float cnt = (float)(re - rs);
      #pragma unroll
      for (int j = 0; j < 8; j++) tot[j] += cnt * bnsh[type*128 + c8 + j];
    }
  }
  #pragma unroll
  for (int j = 0; j < 8; j++) red[rt][c8 + j] = tot[j];
  __syncthreads();
  if (tid < 128) {
    float s = 0.f;
    #pragma unroll
    for (int i = 0; i < 16; i++) s += red[i][tid];
    feats[(size_t)g*FD + tid] = s * invcnt[g];
  }
}

__global__ __launch_bounds__(256) void k_heads(const float* __restrict__ feats,
                                               const float* __restrict__ fcW,
                                               const float* __restrict__ fcb,
                                               float* __restrict__ logits) {
  int idx = blockIdx.x*256 + threadIdx.x;
  if (idx >= LOGITS_N) return;
  int l = idx >> 13;
  int rem = idx & 8191;
  int g = rem >> 4;
  int c = rem & 15;
  const float* f = feats + ((size_t)l*NG + g)*FD;
  const float* w = fcW + ((size_t)l*NC + c)*FD;
  float s = 0.f;
  #pragma unroll
  for (int k = 0; k < FD; k += 4) {
    float4 fv = *(const float4*)(f + k);
    float4 wv = *(const float4*)(w + k);
    s += fv.x*wv.x + fv.y*wv.y + fv.z*wv.z + fv.w*wv.w;
  }
  logits[idx] = s + fcb[l*NC + c];
}

extern "C" void kernel_launch(void* const* d_in, const int* in_sizes, int n_in,
                              void* d_out, int out_size, void* d_ws, size_t ws_size,
                              hipStream_t stream) {
  const float* x_user   = (const float*)d_in[0];
  const float* x_item   = (const float*)d_in[1];
  const int*   eu2i     = (const int*)d_in[2];
  const int*   ei2u     = (const int*)d_in[3];
  const int*   bu       = (const int*)d_in[4];
  const int*   bi       = (const int*)d_in[5];
  const float* Wrel_u2i = (const float*)d_in[6];
  const float* Wroot_u2i= (const float*)d_in[7];
  const float* b_u2i    = (const float*)d_in[8];
  const float* Wrel_i2u = (const float*)d_in[9];
  const float* Wroot_i2u= (const float*)d_in[10];
  const float* b_i2u    = (const float*)d_in[11];
  const float* bn_g_user= (const float*)d_in[12];
  const float* bn_b_user= (const float*)d_in[13];
  const float* bn_g_item= (const float*)d_in[14];
  const float* bn_b_item= (const float*)d_in[15];
  const float* fcW      = (const float*)d_in[16];
  const float* fcb      = (const float*)d_in[17];

  char* ws = (char*)d_ws;
  int*   gcnt   = (int*)(ws + OFF_GCNT);
  int*   bcursor= (int*)(ws + OFF_BCUR);
  float* accSQ  = (float*)(ws + OFF_ACC);
  int*   ustart = (int*)(ws + OFF_USTART);
  int*   istart = (int*)(ws + OFF_ISTART);
  float* invcnt = (float*)(ws + OFF_INVCNT);
  float* bnsc   = (float*)(ws + OFF_BNSC);
  float* bnsh   = (float*)(ws + OFF_BNSH);
  int2*  rowrange = (int2*)(ws + OFF_ROWRANGE);
  u16*   WB     = (u16*)(ws + OFF_WB);
  int*   csrbin = (int*)(ws + OFF_CSR);
  u16*   n0I    = (u16*)(ws + OFF_N0I);
  u16*   n0U    = (u16*)(ws + OFF_N0U);
  u16*   n1U    = (u16*)(ws + OFF_N1U);
  u16*   n1I    = (u16*)(ws + OFF_N1I);
  u16*   xu0    = (u16*)(ws + OFF_XU0);
  u16*   xi0    = (u16*)(ws + OFF_XI0);
  u16*   WBs    = (u16*)(ws + OFF_WBS);
  float* bvec   = (float*)(ws + OFF_BVEC);
  float* fout   = (float*)d_out;
  float* featsAll = fout + LOGITS_N;

  hipMemsetAsync(ws, 0, MEMSET_BYTES, stream);
  k_hist_batch<<<NBLK, 256, 0, stream>>>(bu, bi, gcnt);
  k_bin<<<NBINBLK, 256, 0, stream>>>(eu2i, ei2u, bcursor, csrbin);
  k_scan_g<<<1, 512, 0, stream>>>(gcnt, ustart, istart, invcnt);
  k_csrbuild<<<NBUCK, 256, 0, stream>>>(bcursor, csrbin, rowrange);
  k_castX<<<12500, 256, 0, stream>>>(x_user, x_item, xu0, xi0);
  k_castW<<<256, 256, 0, stream>>>(Wrel_u2i, Wroot_u2i, Wrel_i2u, Wroot_i2u, WB);

  // ---- layer 0: sources are raw inputs (no relu, no BN fold) ----
  k_gather<0><<<25000, 256, 0, stream>>>(xu0, xi0, rowrange, csrbin, n0I, n0U);
  k_gemm<<<dim3(NBLK,2), 256, 0, stream>>>(n0U, n0I, xu0, xi0, WB,
                                           b_i2u, b_u2i, accSQ,
                                           bvec, rowrange, 0);
  k_bnfinal<<<1, 256, 0, stream>>>(accSQ, bn_g_user, bn_b_user,
                                   bn_g_item, bn_b_item, bnsc, bnsh);
  k_bnfold<<<66, 256, 0, stream>>>(Wrel_u2i, Wroot_u2i, Wrel_i2u, Wroot_i2u,
                                   1, bnsc, bnsh, WBs, bvec);
  k_pool<<<NG, 256, 0, stream>>>(n0U, n0I, ustart, istart, bnsc, bnsh,
                                 invcnt, featsAll);

  // ---- layer 1: relu in gather/staging, BN folded into WBs/bvec ----
  k_gather<1><<<25000, 256, 0, stream>>>(n0U, n0I, rowrange, csrbin, n1I, n1U);
  k_gemm<<<dim3(NBLK,2), 256, 0, stream>>>(n1U, n1I, n0U, n0I, WBs,
                                           b_i2u + FD, b_u2i + FD, accSQ,
                                           bvec, rowrange, 1);
  k_bnfinal<<<1, 256, 0, stream>>>(accSQ, bn_g_user, bn_b_user,
                                   bn_g_item, bn_b_item, bnsc, bnsh);
  k_bnfold<<<66, 256, 0, stream>>>(Wrel_u2i, Wroot_u2i, Wrel_i2u, Wroot_i2u,
                                   2, bnsc, bnsh, WBs, bvec);
  k_pool<<<NG, 256, 0, stream>>>(n1U, n1I, ustart, istart, bnsc, bnsh,
                                 invcnt, featsAll + NG*FD);

  // ---- layer 2 ----
  k_gather<1><<<25000, 256, 0, stream>>>(n1U, n1I, rowrange, csrbin, n0I, n0U);
  k_gemm<<<dim3(NBLK,2), 256, 0, stream>>>(n0U, n0I, n1U, n1I, WBs,
                                           b_i2u + 2*FD, b_u2i + 2*FD, accSQ,
                                           bvec, rowrange, 1);
  k_bnfinal<<<1, 256, 0, stream>>>(accSQ, bn_g_user, bn_b_user,
                                   bn_g_item, bn_b_item, bnsc, bnsh);
  k_pool<<<NG, 256, 0, stream>>>(n0U, n0I, ustart, istart, bnsc, bnsh,
                                 invcnt, featsAll + 2*NG*FD);

  k_heads<<<96, 256, 0, stream>>>(featsAll, fcW, fcb, fout);
}

// Round 2
// 521.924 us; speedup vs baseline: 1.0267x; 1.0267x over previous
//
#include <hip/hip_runtime.h>

#define NN 50000
#define FD 128
#define NE 800000
#define NG 512
#define NC 16
#define NL 3
#define NTOT 100000
#define NBLK 391            // ceil(100000/256) and ceil(50000/128)
#define NBUCK 196           // ceil(100000/512) slot-buckets
#define CAP 10240           // per-bucket capacity (avg 8163, sigma ~90)
#define BINTILE 2048
#define NBINBLK 782         // ceil(1600000/2048)
#define BNEPS 1e-5f
#define LOGITS_N (NL*NG*NC)

typedef unsigned short u16;
typedef unsigned char u8;
typedef __attribute__((ext_vector_type(8))) short short8;
typedef __attribute__((ext_vector_type(4))) float f32x4;

// ---- workspace layout (bytes), offsets 512-aligned ----
#define OFF_GCNT     0ul          // 2*512 int
#define OFF_BCUR     4096ul       // 196 int (per-bucket fill count)
#define OFF_ACC      5120ul       // 512 f32 (BN stat accumulators: S[256],Q[256])
#define MEMSET_BYTES 7168ul       // covers GCNT + BCUR + ACC
#define OFF_USTART   7680ul       // 513 int
#define OFF_ISTART   10240ul      // 513 int
#define OFF_INVCNT   12800ul      // 512 f32
#define OFF_BNSC     14848ul      // 256 f32
#define OFF_BNSH     15872ul      // 256 f32
#define OFF_ROWRANGE 16896ul      // 100000 int2
#define OFF_WB       817152ul     // 6*128*256 bf16 (only layer-0 block used now)
#define OFF_CSR      1210368ul    // 196*10240 int (binned, then CSR in place)
#define OFF_N0I      9238528ul    // 50000*128 bf16 (ping-pong pair 0, item)
#define OFF_N0U      22038528ul   // 50000*128 bf16 (ping-pong pair 0, user)
#define OFF_N1U      34838528ul   // 50000*128 bf16 (ping-pong pair 1, user)
#define OFF_N1I      47638528ul   // 50000*128 bf16 (ping-pong pair 1, item)
#define OFF_XU0      60438528ul   // 50000*128 bf16 (initial cast)
#define OFF_XI0      73238528ul   // 50000*128 bf16 (initial cast)
// WBs/bvec overlap the head of xi0: xi0 is only read by layer-0 gather/gemm,
// both of which complete before the first k_bnfold2 writes here.
#define OFF_WBS      73238528ul   // 2*128*256 bf16 scaled weights (current layer)
#define OFF_BVEC     73369600ul   // b1[2][128] | b2[2][128] f32 fold vectors

static __device__ __forceinline__ float bf2f(u16 v) {
  return __uint_as_float(((unsigned)v) << 16);
}
static __device__ __forceinline__ u16 f2bf(float f) {
  unsigned u = __float_as_uint(f);
  return (u16)((u + 0x7FFFu + ((u >> 16) & 1u)) >> 16);
}
// accumulate 8 packed bf16 (int4) into float[8]; RELU=1 applies max(0,.) per elem
template<int RELU>
static __device__ __forceinline__ void accT8(float* a, int4 v) {
  unsigned w[4] = {(unsigned)v.x, (unsigned)v.y, (unsigned)v.z, (unsigned)v.w};
  #pragma unroll
  for (int i = 0; i < 4; i++) {
    float lo = __uint_as_float(w[i] << 16);
    float hi = __uint_as_float(w[i] & 0xffff0000u);
    if (RELU) { lo = lo > 0.f ? lo : 0.f; hi = hi > 0.f ? hi : 0.f; }
    a[2*i]   += lo;
    a[2*i+1] += hi;
  }
}
// unpack 8 bf16 (int4) into float[8]
static __device__ __forceinline__ void unp8(float* a, int4 v) {
  a[0] = __uint_as_float(((unsigned)v.x) << 16);
  a[1] = __uint_as_float(((unsigned)v.x) & 0xffff0000u);
  a[2] = __uint_as_float(((unsigned)v.y) << 16);
  a[3] = __uint_as_float(((unsigned)v.y) & 0xffff0000u);
  a[4] = __uint_as_float(((unsigned)v.z) << 16);
  a[5] = __uint_as_float(((unsigned)v.z) & 0xffff0000u);
  a[6] = __uint_as_float(((unsigned)v.w) << 16);
  a[7] = __uint_as_float(((unsigned)v.w) & 0xffff0000u);
}
// relu on 2 packed bf16 without unpacking (zero any half with sign bit set)
static __device__ __forceinline__ int relu2(int w) {
  int lo = (w & 0x00008000) ? 0 : (w & 0x0000FFFF);
  int hi = (w < 0)          ? 0 : (int)(w & 0xFFFF0000u);
  return lo | hi;
}

__global__ __launch_bounds__(256) void k_hist_batch(const int* __restrict__ bu,
                                                    const int* __restrict__ bi,
                                                    int* __restrict__ gcnt) {
  int i = blockIdx.x*256 + threadIdx.x;
  if (i >= NTOT) return;
  int type = i >= NN;
  int g = type ? bi[i-NN] : bu[i];
  atomicAdd(&gcnt[type*NG + g], 1);
}

// scan per-type graph counts -> contiguous row ranges (batch ids are sorted)
__global__ __launch_bounds__(512) void k_scan_g(const int* __restrict__ gcnt,
                                                int* __restrict__ ustart,
                                                int* __restrict__ istart,
                                                float* __restrict__ invcnt) {
  __shared__ int pu[512], pi[512];
  int t = threadIdx.x;
  int cu = gcnt[t], ci = gcnt[NG + t];
  pu[t] = cu; pi[t] = ci;
  __syncthreads();
  for (int off = 1; off < 512; off <<= 1) {
    int vu = (t >= off) ? pu[t-off] : 0;
    int vi = (t >= off) ? pi[t-off] : 0;
    __syncthreads();
    pu[t] += vu; pi[t] += vi;
    __syncthreads();
  }
  ustart[t] = pu[t] - cu;
  istart[t] = pi[t] - ci;
  if (t == 511) { ustart[NG] = pu[511]; istart[NG] = pi[511]; }
  int c = cu + ci;
  invcnt[t] = 1.0f / (float)(c > 0 ? c : 1);
}

// bucket edges by dst-slot>>9 into fixed-capacity regions. Entry packed to 4B:
// (lslot:9 | src:17). Coalesced run writes via LDS reorder. 2048-edge tiles.
__global__ __launch_bounds__(256) void k_bin(const int* __restrict__ eu2i,
                                             const int* __restrict__ ei2u,
                                             int* __restrict__ bcursor,
                                             int* __restrict__ binned) {
  __shared__ int hist[256];
  __shared__ int scan[256];
  __shared__ int gbase[256];
  __shared__ int rbuf[BINTILE];
  __shared__ u8 rbk[BINTILE];
  int tid = threadIdx.x;
  int base = blockIdx.x * BINTILE;
  hist[tid] = 0;
  __syncthreads();
  int packr[8], bkr[8], rankr[8];
  #pragma unroll
  for (int c = 0; c < 8; c++) {
    int idx = base + c*256 + tid;
    if (idx < 2*NE) {
      int rel = idx >= NE;
      int e = rel ? idx - NE : idx;
      const int* edge = rel ? ei2u : eu2i;
      int s = edge[e];
      int d = edge[NE + e];
      int slot = d + (rel ? NN : 0);
      int bk = slot >> 9;
      bkr[c] = bk;
      packr[c] = ((slot & 511) << 17) | s;
      rankr[c] = atomicAdd(&hist[bk], 1);
    } else bkr[c] = -1;
  }
  __syncthreads();
  scan[tid] = hist[tid];
  __syncthreads();
  for (int o = 1; o < 256; o <<= 1) {
    int v = (tid >= o) ? scan[tid - o] : 0;
    __syncthreads();
    scan[tid] += v;
    __syncthreads();
  }
  if (tid < NBUCK && hist[tid] > 0)
    gbase[tid] = atomicAdd(&bcursor[tid], hist[tid]);
  __syncthreads();
  #pragma unroll
  for (int c = 0; c < 8; c++) {
    if (bkr[c] >= 0) {
      int bk = bkr[c];
      int lpos = scan[bk] - hist[bk] + rankr[c];
      rbuf[lpos] = packr[c];
      rbk[lpos] = (u8)bk;
    }
  }
  __syncthreads();
  int nv = min(BINTILE, 2*NE - base);
  for (int j = tid; j < nv; j += 256) {
    int bk = rbk[j];
    int outpos = bk*CAP + gbase[bk] + (j - (scan[bk] - hist[bk]));
    binned[outpos] = rbuf[j];
  }
}

// one block per bucket: local hist+scan -> rowrange, LDS-staged scatter,
// CSR written IN PLACE over the binned region (block-private).
__global__ __launch_bounds__(256) void k_csrbuild(const int* __restrict__ bcursor,
                                                  int* __restrict__ csrbin,
                                                  int2* __restrict__ rowrange) {
  __shared__ int lcnt[512];
  __shared__ int scan2[256];
  __shared__ int lcsr[CAP];
  int b = blockIdx.x;
  int tid = threadIdx.x;
  int slot0 = b << 9;
  int nslots = min(512, NTOT - slot0);
  int n = bcursor[b];
  int gb = b * CAP;
  lcnt[tid] = 0; lcnt[tid + 256] = 0;
  __syncthreads();
  for (int i = tid; i < n; i += 256) {
    int e = csrbin[gb + i];
    atomicAdd(&lcnt[e >> 17], 1);
  }
  __syncthreads();
  int v0 = lcnt[2*tid], v1 = lcnt[2*tid + 1];
  int ps = v0 + v1;
  scan2[tid] = ps;
  __syncthreads();
  for (int o = 1; o < 256; o <<= 1) {
    int v = (tid >= o) ? scan2[tid - o] : 0;
    __syncthreads();
    scan2[tid] += v;
    __syncthreads();
  }
  int e0 = scan2[tid] - ps;       // exclusive prefix for slot 2*tid
  int e1 = e0 + v0;
  if (2*tid < nslots)     rowrange[slot0 + 2*tid]     = make_int2(gb + e0, gb + e0 + v0);
  if (2*tid + 1 < nslots) rowrange[slot0 + 2*tid + 1] = make_int2(gb + e1, gb + e1 + v1);
  __syncthreads();
  lcnt[2*tid] = e0; lcnt[2*tid + 1] = e1;   // cursors
  __syncthreads();
  for (int i = tid; i < n; i += 256) {
    int e = csrbin[gb + i];
    int pos = atomicAdd(&lcnt[e >> 17], 1);
    lcsr[pos] = e & 0x1FFFF;
  }
  __syncthreads();
  for (int i = tid; i < n; i += 256) csrbin[gb + i] = lcsr[i];
}

// fp32 -> bf16 cast of initial features
__global__ __launch_bounds__(256) void k_castX(const float* __restrict__ xu,
                                               const float* __restrict__ xi,
                                               u16* __restrict__ xbu,
                                               u16* __restrict__ xbi) {
  int b = blockIdx.x;
  int half = b >= 6250;
  const float* src = half ? xi : xu;
  u16* dst = half ? xbi : xbu;
  int i = ((half ? b - 6250 : b)*256 + threadIdx.x) * 4;
  float4 v = *(const float4*)(src + i);
  ushort4 o = { f2bf(v.x), f2bf(v.y), f2bf(v.z), f2bf(v.w) };
  *(ushort4*)(dst + i) = o;
}

// WB[lr][h][k]: k<128 -> Wrel[l][h][k], else Wroot[l][h][k-128]   (bf16)
// launched with 256 blocks: only layer-0 (lr 0,1) weights needed unscaled.
__global__ __launch_bounds__(256) void k_castW(const float* __restrict__ WrelA,
                                               const float* __restrict__ WrootA,
                                               const float* __restrict__ WrelB,
                                               const float* __restrict__ WrootB,
                                               u16* __restrict__ WB) {
  int idx = blockIdx.x*256 + threadIdx.x;
  int lr = idx >> 15;
  int rem = idx & 32767;
  int h = rem >> 8;
  int k = rem & 255;
  int l = lr >> 1;
  int rel = lr & 1;
  const float* Wr = rel ? WrelB : WrelA;
  const float* Wo = rel ? WrootB : WrootA;
  float v = (k < FD) ? Wr[(l*FD + h)*FD + k] : Wo[(l*FD + h)*FD + (k-FD)];
  WB[idx] = f2bf(v);
}

// merged BN finalize + fold (1 launch instead of 2):
// every block recomputes sc/sh from accSQ (bit-identical to old k_bnfinal).
// blocks [0,64): WBs[rel][h][k] scaled weights for layer l
// blocks [64,66): bvec  b1 = Wrel@sh_src (deg-scaled), b2 = Wroot@sh_dst
// last block: write bnsc/bnsh for k_pool. accSQ is zeroed later by k_pool.
// Launched with grid=1 after the last layer -> finalize-only.
__global__ __launch_bounds__(256) void k_bnfold2(const float* __restrict__ WrelA,
                                                 const float* __restrict__ WrootA,
                                                 const float* __restrict__ WrelB,
                                                 const float* __restrict__ WrootB,
                                                 int l,
                                                 const float* __restrict__ accSQ,
                                                 const float* __restrict__ gu,
                                                 const float* __restrict__ bu_,
                                                 const float* __restrict__ gi,
                                                 const float* __restrict__ bi_,
                                                 u16* __restrict__ WBs,
                                                 float* __restrict__ bvec,
                                                 float* __restrict__ bnsc,
                                                 float* __restrict__ bnsh) {
  __shared__ float sc_l[256], sh_l[256];
  int tid = threadIdx.x;
  {
    int type = tid >> 7;
    int c = tid & 127;
    float s = accSQ[tid];
    float q = accSQ[256 + tid];
    float inv = 1.0f / (float)NN;
    float mean = s * inv;
    float var = q * inv - mean*mean;
    float rstd = rsqrtf(var + BNEPS);
    float g = type ? gi[c] : gu[c];
    float bb = type ? bi_[c] : bu_[c];
    float sc = rstd * g;
    sc_l[tid] = sc;
    sh_l[tid] = bb - mean * sc;
  }
  __syncthreads();
  int b = blockIdx.x;
  int lastb = gridDim.x - 1;
  if (b == lastb) {
    bnsc[tid] = sc_l[tid];
    bnsh[tid] = sh_l[tid];
  } else if (b < 64) {
    int e = b*256 + tid;          // 16384 entries x 4 consecutive k
    int rel = e >> 13;
    int rem = e & 8191;
    int h = rem >> 6;
    int k0 = (rem & 63) * 4;
    const float* Wr = rel ? WrelB : WrelA;
    const float* Wo = rel ? WrootB : WrootA;
    const float* scs = sc_l + (rel ? 128 : 0);
    const float* scd = sc_l + (rel ? 0 : 128);
    u16 t[4];
    #pragma unroll
    for (int j = 0; j < 4; j++) {
      int k = k0 + j;
      float v = (k < FD) ? Wr[((size_t)l*FD + h)*FD + k] * scs[k]
                         : Wo[((size_t)l*FD + h)*FD + (k - FD)] * scd[k - FD];
      t[j] = f2bf(v);
    }
    ushort4 o = { t[0], t[1], t[2], t[3] };
    *(ushort4*)(WBs + rel*32768 + h*256 + k0) = o;
  } else {
    int vid = (b - 64)*256 + tid; // 0..511
    int kind = vid >> 8;          // 0 = b1 (Wrel, sh_src), 1 = b2 (Wroot, sh_dst)
    int rel = (vid >> 7) & 1;
    int h = vid & 127;
    const float* W = kind ? (rel ? WrootB : WrootA) : (rel ? WrelB : WrelA);
    const float* sh = sh_l + ((kind ^ rel) ? 128 : 0);
    const float* wrow = W + ((size_t)l*FD + h)*FD;
    float s = 0.f;
    #pragma unroll
    for (int k = 0; k < FD; k += 4) {
      float4 wv = *(const float4*)(wrow + k);
      float4 sv = { sh[k], sh[k+1], sh[k+2], sh[k+3] };
      s += wv.x*sv.x + wv.y*sv.y + wv.z*sv.z + wv.w*sv.w;
    }
    bvec[kind*256 + rel*128 + h] = s;
  }
}

// one wave per dst row; 16B/lane loads (16 lanes = one 256B row), quarter-waves
// take different edges; 2 chains x 8-edge iters with index prefetch.
// RELU=1 (layers >0): sources are raw pre-BN activations; relu applied
// in-register, BN affine folded downstream into GEMM weights/bias.
// blocks [0,12500): u2i (curU -> aggI), [12500,25000): i2u (curI -> aggU)
template<int RELU>
__global__ __launch_bounds__(256) void k_gather(const u16* __restrict__ curU,
                                                const u16* __restrict__ curI,
                                                const int2* __restrict__ rowrange,
                                                const int* __restrict__ csr,
                                                u16* __restrict__ aggI,
                                                u16* __restrict__ aggU) {
  int b = blockIdx.x;
  int half = b >= 12500;
  int blk = half ? b - 12500 : b;
  const u16* src = half ? curI : curU;
  u16* out = half ? aggU : aggI;
  int slotbase = half ? NN : 0;
  int wid = __builtin_amdgcn_readfirstlane(threadIdx.x >> 6);
  int row = blk*4 + wid;
  int lane = threadIdx.x & 63;
  int q = lane >> 4;
  int c16 = (lane & 15) * 8;      // 8 bf16 = 16B per lane
  const u16* sp = src + c16;
  int2 pr = rowrange[slotbase + row];
  int p = pr.x, pe = pr.y;
  float a0[8], a1[8];
  #pragma unroll
  for (int j = 0; j < 8; j++) { a0[j] = 0.f; a1[j] = 0.f; }
  if (p + 8 <= pe) {
    int i0 = csr[p + q], i1 = csr[p + 4 + q];
    while (p + 16 <= pe) {
      int n0 = csr[p + 8 + q], n1 = csr[p + 12 + q];
      int4 v0 = *(const int4*)(sp + (size_t)i0*FD);
      int4 v1 = *(const int4*)(sp + (size_t)i1*FD);
      accT8<RELU>(a0, v0); accT8<RELU>(a1, v1);
      i0 = n0; i1 = n1; p += 8;
    }
    int4 v0 = *(const int4*)(sp + (size_t)i0*FD);
    int4 v1 = *(const int4*)(sp + (size_t)i1*FD);
    accT8<RELU>(a0, v0); accT8<RELU>(a1, v1);
    p += 8;
  }
  int rem = pe - p;               // 0..7
  if (q < rem) {
    int s = csr[p + q];
    accT8<RELU>(a0, *(const int4*)(sp + (size_t)s*FD));
  }
  if (q + 4 < rem) {
    int s = csr[p + 4 + q];
    accT8<RELU>(a1, *(const int4*)(sp + (size_t)s*FD));
  }
  #pragma unroll
  for (int j = 0; j < 8; j++) a0[j] += a1[j];
  #pragma unroll
  for (int j = 0; j < 8; j++) {
    a0[j] += __shfl_xor(a0[j], 16);
    a0[j] += __shfl_xor(a0[j], 32);
  }
  if (q == 0) {
    int4 o;
    o.x = (unsigned)f2bf(a0[0]) | ((unsigned)f2bf(a0[1]) << 16);
    o.y = (unsigned)f2bf(a0[2]) | ((unsigned)f2bf(a0[3]) << 16);
    o.z = (unsigned)f2bf(a0[4]) | ((unsigned)f2bf(a0[5]) << 16);
    o.w = (unsigned)f2bf(a0[6]) | ((unsigned)f2bf(a0[7]) << 16);
    *(int4*)(out + (size_t)row*FD + c16) = o;
  }
}

// MFMA bf16 GEMM: new[n,h] = [agg|cur][n,0:256] @ WB[h,0:256]^T + bias'[n,h]
// 128x128 tile, BK=64, LDS row stride 72 bf16. BN relu-stats -> global atomics.
// fold=1 (layers >0): weights pre-scaled (WBs), cur rows relu'd on staging,
// bias' = bias + b2 + deg(row)*b1. Epilogue: LDS transpose (C[128][132]) then
// fully-coalesced int4 stores (8/thread) -- replaces 64 scalar u16 stores.
__global__ __launch_bounds__(256) void k_gemm(u16* __restrict__ newU,
                                              u16* __restrict__ newI,
                                              const u16* __restrict__ curU,
                                              const u16* __restrict__ curI,
                                              const u16* __restrict__ WBl,
                                              const float* __restrict__ bI2U,
                                              const float* __restrict__ bU2I,
                                              float* __restrict__ accSQ,
                                              const float* __restrict__ bvec,
                                              const int2* __restrict__ rowrange,
                                              int fold) {
  __shared__ u16 smem[128*72*2];            // As | Bs, reused as C[128][132]
  __shared__ float Sred[2][4][128];
  u16* As = smem;
  u16* Bs = smem + 128*72;
  u16* Cs = smem;                           // 128*132 = 16896 u16 <= 18432
  int ty = blockIdx.y;
  u16* A1 = ty ? newI : newU;
  const u16* A2 = ty ? curI : curU;
  const u16* WBp = ty ? WBl : (WBl + 32768);
  const float* bias = ty ? bU2I : bI2U;
  const float* b1p = bvec + (ty ? 0 : 128);
  const float* b2p = bvec + 256 + (ty ? 0 : 128);
  int slot0 = ty ? 0 : NN;        // dst slots: items [0,NN), users [NN,2NN)
  int tid = threadIdx.x;
  int n0 = blockIdx.x * 128;
  int w = __builtin_amdgcn_readfirstlane(tid >> 6);
  int lane = tid & 63;
  int l15 = lane & 15;
  int quad = lane >> 4;
  f32x4 acc[2][8];
  #pragma unroll
  for (int tr = 0; tr < 2; tr++)
    #pragma unroll
    for (int tc = 0; tc < 8; tc++)
      acc[tr][tc] = (f32x4){0.f,0.f,0.f,0.f};

  for (int ch = 0; ch < 4; ch++) {
    const u16* Ap = (ch < 2) ? ((const u16*)A1 + ch*64) : (A2 + (ch-2)*64);
    int dorelu = fold && (ch >= 2);
    #pragma unroll
    for (int i = 0; i < 4; i++) {
      int e = i*256 + tid;
      int r = e >> 3, seg = e & 7;
      int4 v = {0,0,0,0};
      int gr = n0 + r;
      if (gr < NN) v = *(const int4*)(Ap + (size_t)gr*FD + seg*8);
      if (dorelu) { v.x = relu2(v.x); v.y = relu2(v.y); v.z = relu2(v.z); v.w = relu2(v.w); }
      *(int4*)&As[r*72 + seg*8] = v;
    }
    #pragma unroll
    for (int i = 0; i < 4; i++) {
      int e = i*256 + tid;
      int r = e >> 3, seg = e & 7;
      int4 v = *(const int4*)(WBp + r*256 + ch*64 + seg*8);
      *(int4*)&Bs[r*72 + seg*8] = v;
    }
    __syncthreads();
    #pragma unroll
    for (int ks = 0; ks < 2; ks++) {
      int kb = ks*32 + quad*8;
      short8 af0 = *(const short8*)&As[(w*32 + l15)*72 + kb];
      short8 af1 = *(const short8*)&As[(w*32 + 16 + l15)*72 + kb];
      short8 bf[8];
      #pragma unroll
      for (int tc = 0; tc < 8; tc++)
        bf[tc] = *(const short8*)&Bs[(tc*16 + l15)*72 + kb];
      #pragma unroll
      for (int tc = 0; tc < 8; tc++) {
        acc[0][tc] = __builtin_amdgcn_mfma_f32_16x16x32_bf16(af0, bf[tc], acc[0][tc], 0, 0, 0);
        acc[1][tc] = __builtin_amdgcn_mfma_f32_16x16x32_bf16(af1, bf[tc], acc[1][tc], 0, 0, 0);
      }
    }
    __syncthreads();
  }
  float sv[8], qv[8], bj[8], b1j[8];
  #pragma unroll
  for (int tc = 0; tc < 8; tc++) {
    int col = tc*16 + l15;
    float base = bias[col];
    if (fold) { base += b2p[col]; b1j[tc] = b1p[col]; } else b1j[tc] = 0.f;
    bj[tc] = base;
    sv[tc] = 0.f; qv[tc] = 0.f;
  }
  float dg[2][4] = {{0.f,0.f,0.f,0.f},{0.f,0.f,0.f,0.f}};
  if (fold) {
    #pragma unroll
    for (int tr = 0; tr < 2; tr++)
      #pragma unroll
      for (int gq = 0; gq < 4; gq++) {
        int r = n0 + w*32 + tr*16 + quad*4 + gq;
        if (r < NN) {
          int2 rr = rowrange[slot0 + r];
          dg[tr][gq] = (float)(rr.y - rr.x);
        }
      }
  }
  #pragma unroll
  for (int tr = 0; tr < 2; tr++) {
    int rl0 = w*32 + tr*16 + quad*4;
    int rbase = n0 + rl0;
    #pragma unroll
    for (int tc = 0; tc < 8; tc++) {
      int col = tc*16 + l15;
      #pragma unroll
      for (int g = 0; g < 4; g++) {
        int r = rbase + g;
        float v = acc[tr][tc][g] + bj[tc] + dg[tr][g]*b1j[tc];
        Cs[(rl0 + g)*132 + col] = f2bf(v);
        if (r < NN) {
          float y = v > 0.f ? v : 0.f;
          sv[tc] += y; qv[tc] += y*y;
        }
      }
    }
  }
  #pragma unroll
  for (int tc = 0; tc < 8; tc++) {
    sv[tc] += __shfl_xor(sv[tc], 16); qv[tc] += __shfl_xor(qv[tc], 16);
    sv[tc] += __shfl_xor(sv[tc], 32); qv[tc] += __shfl_xor(qv[tc], 32);
  }
  if (quad == 0) {
    #pragma unroll
    for (int tc = 0; tc < 8; tc++) {
      Sred[0][w][tc*16 + l15] = sv[tc];
      Sred[1][w][tc*16 + l15] = qv[tc];
    }
  }
  __syncthreads();          // covers Cs writes + Sred writes
  if (tid < 128) {
    float s = Sred[0][0][tid] + Sred[0][1][tid] + Sred[0][2][tid] + Sred[0][3][tid];
    float q = Sred[1][0][tid] + Sred[1][1][tid] + Sred[1][2][tid] + Sred[1][3][tid];
    atomicAdd(&accSQ[ty*128 + tid], s);
    atomicAdd(&accSQ[256 + ty*128 + tid], q);
  }
  // coalesced write-back: per pass j, block covers rows j*16..j*16+15 (4 KB)
  int prow = tid >> 4;            // 0..15
  int pc = (tid & 15) * 8;        // u16 col base (16B per lane)
  #pragma unroll
  for (int j = 0; j < 8; j++) {
    int row = j*16 + prow;
    int gr = n0 + row;
    int4 vv = *(const int4*)&Cs[row*132 + pc];
    if (gr < NN) *(int4*)(A1 + (size_t)gr*FD + pc) = vv;
  }
}

// mean-pool over raw pre-BN activations, one block per graph; BN affine
// reconstructed per type:  sc*sum(relu) + n_type*sh.  Read-only on node data.
// block 0 also re-zeroes accSQ for the next layer's gemm (stream-ordered:
// pool runs after bnfold2's accSQ reads and before the next gemm).
__global__ __launch_bounds__(256) void k_pool(const u16* __restrict__ newU,
                                              const u16* __restrict__ newI,
                                              const int* __restrict__ ustart,
                                              const int* __restrict__ istart,
                                              const float* __restrict__ bnsc,
                                              const float* __restrict__ bnsh,
                                              const float* __restrict__ invcnt,
                                              float* __restrict__ feats,
                                              float* __restrict__ accSQ) {
  __shared__ float red[16][128];
  int tid = threadIdx.x;
  int g = blockIdx.x;
  if (g == 0) { accSQ[tid] = 0.f; accSQ[256 + tid] = 0.f; }
  int rt = tid >> 4;        // 0..15 row thread
  int c8 = (tid & 15) * 8;  // col group base
  float tot[8];
  #pragma unroll
  for (int j = 0; j < 8; j++) tot[j] = 0.f;
  #pragma unroll
  for (int type = 0; type < 2; type++) {
    const u16* in = type ? newI : newU;
    const int* st = type ? istart : ustart;
    int rs = st[g], re = st[g+1];
    float acc[8];
    #pragma unroll
    for (int j = 0; j < 8; j++) acc[j] = 0.f;
    int r = rs + rt;
    for (; r + 16 < re; r += 32) {
      int4 v0 = *(const int4*)(in + (size_t)r*FD + c8);
      int4 v1 = *(const int4*)(in + (size_t)(r+16)*FD + c8);
      float f0[8], f1[8];
      unp8(f0, v0); unp8(f1, v1);
      #pragma unroll
      for (int j = 0; j < 8; j++)
        acc[j] += (f0[j] > 0.f ? f0[j] : 0.f) + (f1[j] > 0.f ? f1[j] : 0.f);
    }
    for (; r < re; r += 16) {
      int4 v0 = *(const int4*)(in + (size_t)r*FD + c8);
      float f0[8];
      unp8(f0, v0);
      #pragma unroll
      for (int j = 0; j < 8; j++) acc[j] += f0[j] > 0.f ? f0[j] : 0.f;
    }
    #pragma unroll
    for (int j = 0; j < 8; j++) tot[j] += acc[j] * bnsc[type*128 + c8 + j];
    if (rt == 0) {
      float cnt = (float)(re - rs);
      #pragma unroll
      for (int j = 0; j < 8; j++) tot[j] += cnt * bnsh[type*128 + c8 + j];
    }
  }
  #pragma unroll
  for (int j = 0; j < 8; j++) red[rt][c8 + j] = tot[j];
  __syncthreads();
  if (tid < 128) {
    float s = 0.f;
    #pragma unroll
    for (int i = 0; i < 16; i++) s += red[i][tid];
    feats[(size_t)g*FD + tid] = s * invcnt[g];
  }
}

__global__ __launch_bounds__(256) void k_heads(const float* __restrict__ feats,
                                               const float* __restrict__ fcW,
                                               const float* __restrict__ fcb,
                                               float* __restrict__ logits) {
  int idx = blockIdx.x*256 + threadIdx.x;
  if (idx >= LOGITS_N) return;
  int l = idx >> 13;
  int rem = idx & 8191;
  int g = rem >> 4;
  int c = rem & 15;
  const float* f = feats + ((size_t)l*NG + g)*FD;
  const float* w = fcW + ((size_t)l*NC + c)*FD;
  float s = 0.f;
  #pragma unroll
  for (int k = 0; k < FD; k += 4) {
    float4 fv = *(const float4*)(f + k);
    float4 wv = *(const float4*)(w + k);
    s += fv.x*wv.x + fv.y*wv.y + fv.z*wv.z + fv.w*wv.w;
  }
  logits[idx] = s + fcb[l*NC + c];
}

extern "C" void kernel_launch(void* const* d_in, const int* in_sizes, int n_in,
                              void* d_out, int out_size, void* d_ws, size_t ws_size,
                              hipStream_t stream) {
  const float* x_user   = (const float*)d_in[0];
  const float* x_item   = (const float*)d_in[1];
  const int*   eu2i     = (const int*)d_in[2];
  const int*   ei2u     = (const int*)d_in[3];
  const int*   bu       = (const int*)d_in[4];
  const int*   bi       = (const int*)d_in[5];
  const float* Wrel_u2i = (const float*)d_in[6];
  const float* Wroot_u2i= (const float*)d_in[7];
  const float* b_u2i    = (const float*)d_in[8];
  const float* Wrel_i2u = (const float*)d_in[9];
  const float* Wroot_i2u= (const float*)d_in[10];
  const float* b_i2u    = (const float*)d_in[11];
  const float* bn_g_user= (const float*)d_in[12];
  const float* bn_b_user= (const float*)d_in[13];
  const float* bn_g_item= (const float*)d_in[14];
  const float* bn_b_item= (const float*)d_in[15];
  const float* fcW      = (const float*)d_in[16];
  const float* fcb      = (const float*)d_in[17];

  char* ws = (char*)d_ws;
  int*   gcnt   = (int*)(ws + OFF_GCNT);
  int*   bcursor= (int*)(ws + OFF_BCUR);
  float* accSQ  = (float*)(ws + OFF_ACC);
  int*   ustart = (int*)(ws + OFF_USTART);
  int*   istart = (int*)(ws + OFF_ISTART);
  float* invcnt = (float*)(ws + OFF_INVCNT);
  float* bnsc   = (float*)(ws + OFF_BNSC);
  float* bnsh   = (float*)(ws + OFF_BNSH);
  int2*  rowrange = (int2*)(ws + OFF_ROWRANGE);
  u16*   WB     = (u16*)(ws + OFF_WB);
  int*   csrbin = (int*)(ws + OFF_CSR);
  u16*   n0I    = (u16*)(ws + OFF_N0I);
  u16*   n0U    = (u16*)(ws + OFF_N0U);
  u16*   n1U    = (u16*)(ws + OFF_N1U);
  u16*   n1I    = (u16*)(ws + OFF_N1I);
  u16*   xu0    = (u16*)(ws + OFF_XU0);
  u16*   xi0    = (u16*)(ws + OFF_XI0);
  u16*   WBs    = (u16*)(ws + OFF_WBS);
  float* bvec   = (float*)(ws + OFF_BVEC);
  float* fout   = (float*)d_out;
  float* featsAll = fout + LOGITS_N;

  hipMemsetAsync(ws, 0, MEMSET_BYTES, stream);
  k_hist_batch<<<NBLK, 256, 0, stream>>>(bu, bi, gcnt);
  k_bin<<<NBINBLK, 256, 0, stream>>>(eu2i, ei2u, bcursor, csrbin);
  k_scan_g<<<1, 512, 0, stream>>>(gcnt, ustart, istart, invcnt);
  k_csrbuild<<<NBUCK, 256, 0, stream>>>(bcursor, csrbin, rowrange);
  k_castX<<<12500, 256, 0, stream>>>(x_user, x_item, xu0, xi0);
  k_castW<<<256, 256, 0, stream>>>(Wrel_u2i, Wroot_u2i, Wrel_i2u, Wroot_i2u, WB);

  // ---- layer 0: sources are raw inputs (no relu, no BN fold) ----
  k_gather<0><<<25000, 256, 0, stream>>>(xu0, xi0, rowrange, csrbin, n0I, n0U);
  k_gemm<<<dim3(NBLK,2), 256, 0, stream>>>(n0U, n0I, xu0, xi0, WB,
                                           b_i2u, b_u2i, accSQ,
                                           bvec, rowrange, 0);
  k_bnfold2<<<67, 256, 0, stream>>>(Wrel_u2i, Wroot_u2i, Wrel_i2u, Wroot_i2u,
                                    1, accSQ, bn_g_user, bn_b_user,
                                    bn_g_item, bn_b_item, WBs, bvec, bnsc, bnsh);
  k_pool<<<NG, 256, 0, stream>>>(n0U, n0I, ustart, istart, bnsc, bnsh,
                                 invcnt, featsAll, accSQ);

  // ---- layer 1: relu in gather/staging, BN folded into WBs/bvec ----
  k_gather<1><<<25000, 256, 0, stream>>>(n0U, n0I, rowrange, csrbin, n1I, n1U);
  k_gemm<<<dim3(NBLK,2), 256, 0, stream>>>(n1U, n1I, n0U, n0I, WBs,
                                           b_i2u + FD, b_u2i + FD, accSQ,
                                           bvec, rowrange, 1);
  k_bnfold2<<<67, 256, 0, stream>>>(Wrel_u2i, Wroot_u2i, Wrel_i2u, Wroot_i2u,
                                    2, accSQ, bn_g_user, bn_b_user,
                                    bn_g_item, bn_b_item, WBs, bvec, bnsc, bnsh);
  k_pool<<<NG, 256, 0, stream>>>(n1U, n1I, ustart, istart, bnsc, bnsh,
                                 invcnt, featsAll + NG*FD, accSQ);

  // ---- layer 2 ----
  k_gather<1><<<25000, 256, 0, stream>>>(n1U, n1I, rowrange, csrbin, n0I, n0U);
  k_gemm<<<dim3(NBLK,2), 256, 0, stream>>>(n0U, n0I, n1U, n1I, WBs,
                                           b_i2u + 2*FD, b_u2i + 2*FD, accSQ,
                                           bvec, rowrange, 1);
  k_bnfold2<<<1, 256, 0, stream>>>(Wrel_u2i, Wroot_u2i, Wrel_i2u, Wroot_i2u,
                                   2, accSQ, bn_g_user, bn_b_user,
                                   bn_g_item, bn_b_item, WBs, bvec, bnsc, bnsh);
  k_pool<<<NG, 256, 0, stream>>>(n0U, n0I, ustart, istart, bnsc, bnsh,
                                 invcnt, featsAll + 2*NG*FD, accSQ);

  k_heads<<<96, 256, 0, stream>>>(featsAll, fcW, fcb, fout);
}